// Round 5
// baseline (116.313 us; speedup 1.0000x reference)
//
#include <hip/hip_runtime.h>
#include <stdint.h>

#define BB 4
#define NN 4096
#define CC 256
#define DD 32

typedef __bf16 bf16;
typedef bf16 bf16x4 __attribute__((ext_vector_type(4)));
typedef bf16 bf16x8 __attribute__((ext_vector_type(8)));
typedef float f32x4 __attribute__((ext_vector_type(4)));
typedef unsigned int u32x4 __attribute__((ext_vector_type(4)));

// ---------------- prepw: build WT[320][256] = [Wq|Wk|Wv]^T (bf16) -----------
__global__ void prepw_kernel(const float* __restrict__ Wq,
                             const float* __restrict__ Wk,
                             const float* __restrict__ Wv,
                             bf16* __restrict__ WT)
{
    int i = blockIdx.x * 256 + threadIdx.x;   // grid 320 -> 81920 threads
    if (i < 320 * 256) {
        int d = i >> 8, c = i & 255;
        float val;
        if (d < DD)          val = Wq[c * DD + d];
        else if (d < 2 * DD) val = Wk[c * DD + (d - DD)];
        else                 val = Wv[c * CC + (d - 2 * DD)];
        WT[i] = (bf16)val;
    }
}

// ---------------- proj: [q|k|v] = x @ [Wq|Wk|Wv], f32 x read + in-reg cast --
// Grid 512: block = 32 rows. Waves: rw=w>>1 row-half (16 rows), ch=w&1 ct-half.
// Outputs: qb,kb as [B][N][32] bf16; v transposed+swizzled:
//   vt elem offset = ((b*64 + tile)*256 + c)*64 + (n_in_tile ^ ((c&7)<<3))
__global__ __launch_bounds__(256) void proj_kernel(
    const float* __restrict__ x, const bf16* __restrict__ WT,
    bf16* __restrict__ qb, bf16* __restrict__ kb, bf16* __restrict__ vt)
{
    int b = blockIdx.x >> 7, nt = blockIdx.x & 127;   // 128 tiles of 32 rows
    int n0 = nt << 5;
    int tid = threadIdx.x;
    int w = tid >> 6, lane = tid & 63;
    int lm = lane & 15, g = lane >> 4;
    int rw = w >> 1;    // row half
    int ch = w & 1;     // ct half

    f32x4 acc[10];
    f32x4 zero4 = {0.f, 0.f, 0.f, 0.f};
#pragma unroll
    for (int i = 0; i < 10; ++i) acc[i] = zero4;

    const float* xrow = x + ((size_t)(b * NN) + n0 + rw * 16 + lm) * CC;
    for (int kc = 0; kc < 8; ++kc) {
        f32x4 a0 = *(const f32x4*)(xrow + kc * 32 + g * 8);
        f32x4 a1 = *(const f32x4*)(xrow + kc * 32 + g * 8 + 4);
        bf16x8 a;
        a[0] = (bf16)a0[0]; a[1] = (bf16)a0[1]; a[2] = (bf16)a0[2]; a[3] = (bf16)a0[3];
        a[4] = (bf16)a1[0]; a[5] = (bf16)a1[1]; a[6] = (bf16)a1[2]; a[7] = (bf16)a1[3];
#pragma unroll
        for (int ct = 0; ct < 10; ++ct) {
            int ctg = ch * 10 + ct;
            bf16x8 wv = *(const bf16x8*)(WT + (ctg * 16 + lm) * 256 + kc * 32 + g * 8);
            acc[ct] = __builtin_amdgcn_mfma_f32_16x16x32_bf16(a, wv, acc[ct], 0, 0, 0);
        }
    }

#pragma unroll
    for (int ct = 0; ct < 10; ++ct) {
        int ctg = ch * 10 + ct;
        int col = ctg * 16 + lm;
        if (ctg < 4) {
#pragma unroll
            for (int r = 0; r < 4; ++r) {
                int n = n0 + rw * 16 + g * 4 + r;
                bf16 hv = (bf16)acc[ct][r];
                if (ctg < 2) qb[((size_t)(b * NN) + n) * DD + col] = hv;
                else         kb[((size_t)(b * NN) + n) * DD + (col - DD)] = hv;
            }
        } else {
            int c = col - 64;
            int tile = nt >> 1;
            int nbase = ((nt & 1) * 32 + rw * 16 + g * 4) ^ ((c & 7) << 3);
            bf16x4 pk;
            pk[0] = (bf16)acc[ct][0]; pk[1] = (bf16)acc[ct][1];
            pk[2] = (bf16)acc[ct][2]; pk[3] = (bf16)acc[ct][3];
            size_t off = (((size_t)(b * 64 + tile)) * 256 + c) * 64 + nbase;
            *(bf16x4*)(vt + off) = pk;
        }
    }
}

// ============ attn v5: swapped QK^T, K dbuf + V single-buffer, KS=3 =========
// Block: 64 q-rows x key-slice, 4 waves. Wave w: QK^T (swapped: mfma(K,Q)) for
// q-rows 16w..16w+15 -> lane holds S[qrow=16w+lm][key=16t+4g+r]; softmax is
// in-lane + 2 shfls. P via dbuf LDS; PV channel-split (wave w -> chans
// 64w..64w+63, V quarter in regs). K regs double-buffered (needed at step
// top); V single-buffered, loaded early (consumed ~500cyc later after
// barrier). V issued BEFORE K-prefetch so PV waits vmcnt(4), K stays in
// flight across the raw s_barrier (no vmcnt drain).

#define LOADK(KT_, KF) { \
    const bf16* kbase_ = kb + ((size_t)(b * NN) + (size_t)(KT_) * 64) * DD + g * 8; \
    KF[0] = *(const bf16x8*)(kbase_ + (lm +  0) * DD); \
    KF[1] = *(const bf16x8*)(kbase_ + (lm + 16) * DD); \
    KF[2] = *(const bf16x8*)(kbase_ + (lm + 32) * DD); \
    KF[3] = *(const bf16x8*)(kbase_ + (lm + 48) * DD); }

#define LOADV(KT_) { \
    const bf16* vtile_ = vt + ((size_t)(b * 64 + (KT_))) * 16384; \
    _Pragma("unroll") \
    for (int ct_ = 0; ct_ < 4; ++ct_) { \
        int c_ = 64 * w + 16 * ct_ + lm; \
        const bf16* vrow_ = vtile_ + c_ * 64; \
        int vsw_ = (c_ & 7) << 3; \
        vb[ct_][0] = *(const bf16x8*)(vrow_ + ((8 * g) ^ vsw_)); \
        vb[ct_][1] = *(const bf16x8*)(vrow_ + ((32 + 8 * g) ^ vsw_)); \
    } }

#define STEP(KT_, KF, KFN) { \
    const int cur_ = (KT_) & 1; \
    f32x4 sv0 = __builtin_amdgcn_mfma_f32_16x16x32_bf16(KF[0], qf, zero4, 0, 0, 0); \
    f32x4 sv1 = __builtin_amdgcn_mfma_f32_16x16x32_bf16(KF[1], qf, zero4, 0, 0, 0); \
    f32x4 sv2 = __builtin_amdgcn_mfma_f32_16x16x32_bf16(KF[2], qf, zero4, 0, 0, 0); \
    f32x4 sv3 = __builtin_amdgcn_mfma_f32_16x16x32_bf16(KF[3], qf, zero4, 0, 0, 0); \
    LOADV(KT_); \
    int ktn_ = ((KT_) + 1 < kt1) ? ((KT_) + 1) : (kt1 - 1); \
    LOADK(ktn_, KFN); \
    float mx_ = fmaxf(fmaxf(fmaxf(sv0[0], sv0[1]), fmaxf(sv0[2], sv0[3])), \
                      fmaxf(fmaxf(sv1[0], sv1[1]), fmaxf(sv1[2], sv1[3]))); \
    mx_ = fmaxf(mx_, fmaxf(fmaxf(sv2[0], sv2[1]), fmaxf(sv2[2], sv2[3]))); \
    mx_ = fmaxf(mx_, fmaxf(fmaxf(sv3[0], sv3[1]), fmaxf(sv3[2], sv3[3]))); \
    mx_ = fmaxf(mx_, __shfl_xor(mx_, 16)); \
    mx_ = fmaxf(mx_, __shfl_xor(mx_, 32)); \
    float alpha_; \
    int wave_ok_ = __all(mx_ <= mrun + 8.0f); \
    if (!wave_ok_) { float mn_ = fmaxf(mrun, mx_); alpha_ = __expf(mrun - mn_); mrun = mn_; } \
    else alpha_ = 1.0f; \
    float ssum_; \
    { \
        _Pragma("unroll") for (int j_ = 0; j_ < 4; ++j_) sv0[j_] = __expf(sv0[j_] - mrun); \
        _Pragma("unroll") for (int j_ = 0; j_ < 4; ++j_) sv1[j_] = __expf(sv1[j_] - mrun); \
        _Pragma("unroll") for (int j_ = 0; j_ < 4; ++j_) sv2[j_] = __expf(sv2[j_] - mrun); \
        _Pragma("unroll") for (int j_ = 0; j_ < 4; ++j_) sv3[j_] = __expf(sv3[j_] - mrun); \
        f32x4 t_ = (sv0 + sv1) + (sv2 + sv3); \
        ssum_ = (t_[0] + t_[1]) + (t_[2] + t_[3]); \
        ssum_ += __shfl_xor(ssum_, 16); \
        ssum_ += __shfl_xor(ssum_, 32); \
    } \
    lrun = lrun * alpha_ + ssum_; \
    unsigned char* Pb_ = lds + cur_ * 8192; \
    { \
        int rb_ = (16 * w + lm) * 128; \
        int sw_ = (lm & 7) << 4; \
        bf16x4 pk_; \
        pk_[0] = (bf16)sv0[0]; pk_[1] = (bf16)sv0[1]; pk_[2] = (bf16)sv0[2]; pk_[3] = (bf16)sv0[3]; \
        *(bf16x4*)(Pb_ + rb_ + (( 0 + 8 * g) ^ sw_)) = pk_; \
        pk_[0] = (bf16)sv1[0]; pk_[1] = (bf16)sv1[1]; pk_[2] = (bf16)sv1[2]; pk_[3] = (bf16)sv1[3]; \
        *(bf16x4*)(Pb_ + rb_ + ((32 + 8 * g) ^ sw_)) = pk_; \
        pk_[0] = (bf16)sv2[0]; pk_[1] = (bf16)sv2[1]; pk_[2] = (bf16)sv2[2]; pk_[3] = (bf16)sv2[3]; \
        *(bf16x4*)(Pb_ + rb_ + ((64 + 8 * g) ^ sw_)) = pk_; \
        pk_[0] = (bf16)sv3[0]; pk_[1] = (bf16)sv3[1]; pk_[2] = (bf16)sv3[2]; pk_[3] = (bf16)sv3[3]; \
        *(bf16x4*)(Pb_ + rb_ + ((96 + 8 * g) ^ sw_)) = pk_; \
    } \
    float* alph_ = (float*)(lds + 16384 + cur_ * 512); \
    uint32_t* flg_ = (uint32_t*)(lds + 16384 + cur_ * 512 + 256); \
    if (g == 0) alph_[16 * w + lm] = alpha_; \
    if (lane == 0) flg_[w] = (uint32_t)wave_ok_; \
    asm volatile("s_waitcnt lgkmcnt(0)" ::: "memory"); \
    __builtin_amdgcn_s_barrier(); \
    asm volatile("" ::: "memory"); \
    { \
        u32x4 fl_ = *(const u32x4*)flg_; \
        if ((fl_[0] & fl_[1] & fl_[2] & fl_[3]) == 0u) { \
            _Pragma("unroll") for (int rt_ = 0; rt_ < 4; ++rt_) { \
                f32x4 a_ = *(const f32x4*)(alph_ + rt_ * 16 + 4 * g); \
                _Pragma("unroll") for (int ct_ = 0; ct_ < 4; ++ct_) { \
                    acc[rt_][ct_][0] *= a_[0]; acc[rt_][ct_][1] *= a_[1]; \
                    acc[rt_][ct_][2] *= a_[2]; acc[rt_][ct_][3] *= a_[3]; \
                } \
            } \
        } \
    } \
    __builtin_amdgcn_s_setprio(1); \
    { \
        int psw_ = (lm & 7) << 4; \
        _Pragma("unroll") for (int rt_ = 0; rt_ < 4; ++rt_) { \
            const unsigned char* pr_ = Pb_ + (rt_ * 16 + lm) * 128; \
            bf16x8 pa0_ = *(const bf16x8*)(pr_ + (( 0 + 16 * g) ^ psw_)); \
            bf16x8 pa1_ = *(const bf16x8*)(pr_ + ((64 + 16 * g) ^ psw_)); \
            _Pragma("unroll") for (int ct_ = 0; ct_ < 4; ++ct_) { \
                acc[rt_][ct_] = __builtin_amdgcn_mfma_f32_16x16x32_bf16(pa0_, vb[ct_][0], acc[rt_][ct_], 0, 0, 0); \
                acc[rt_][ct_] = __builtin_amdgcn_mfma_f32_16x16x32_bf16(pa1_, vb[ct_][1], acc[rt_][ct_], 0, 0, 0); \
            } \
        } \
    } \
    __builtin_amdgcn_s_setprio(0); \
}

__global__ __launch_bounds__(256, 3) void attn_kernel(
    const bf16* __restrict__ qb, const bf16* __restrict__ kb,
    const bf16* __restrict__ vt, const float* __restrict__ x,
    const float* __restrict__ gamma, bf16* __restrict__ pacc,
    float* __restrict__ pml, float* __restrict__ out, int KS)
{
    // 2 x 8KB P buffers + 2 x 512B meta (alphas f32[64] @+0, flags u32[4] @+256)
    __shared__ __align__(16) unsigned char lds[17408];
    int bid = blockIdx.x;
    int b, qt, ks;
    if (KS == 3) {
        // XCD-aware decode: batch b -> XCDs {2b,2b+1} so vt/kb stay L2-resident
        int xcd = bid & 7, slot = bid >> 3;      // 768 blocks: slot in [0,96)
        b = xcd >> 1;
        int idx = (xcd & 1) * 96 + slot;         // [0,192) within batch
        qt = idx / 3; ks = idx - qt * 3;
    } else {
        ks = bid % KS; int t = bid / KS; b = t >> 6; qt = t & 63;
    }
    int bq = b * 64 + qt;
    int n0 = qt << 6;
    int tid = threadIdx.x;
    int w = tid >> 6, lane = tid & 63;
    int lm = lane & 15, g = lane >> 4;

    // Q fragment (used as MFMA B-operand: col=qrow=lm, k=8g..8g+7)
    bf16x8 qf = *(const bf16x8*)(qb + ((size_t)(b * NN) + n0 + w * 16 + lm) * DD + g * 8);

    f32x4 acc[4][4]; // [row-tile][chan-tile], rows rt*16+4g+r, chans 64w+16ct+lm
    f32x4 zero4 = {0.f, 0.f, 0.f, 0.f};
#pragma unroll
    for (int i = 0; i < 4; ++i)
#pragma unroll
        for (int j = 0; j < 4; ++j) acc[i][j] = zero4;
    float mrun = -1e30f, lrun = 0.f;

    int kt0 = (64 * ks) / KS;
    int kt1 = (64 * (ks + 1)) / KS;

    bf16x8 kfA[4], kfB[4];
    bf16x8 vb[4][2];
    LOADK(kt0, kfA);

    int kt = kt0;
    while (kt + 2 <= kt1) {
        STEP(kt,     kfA, kfB);
        STEP(kt + 1, kfB, kfA);
        kt += 2;
    }
    if (kt < kt1) {
        STEP(kt, kfA, kfB);
    }

    if (KS == 1) {
        __syncthreads();
        float* lsh = (float*)(lds + 16384);
        if (g == 0) lsh[16 * w + lm] = lrun;
        __syncthreads();
        float gam = gamma[0];
#pragma unroll
        for (int rt = 0; rt < 4; ++rt) {
            f32x4 lv = *(const f32x4*)(lsh + rt * 16 + 4 * g);
            f32x4 inv;
            inv[0] = 1.f / lv[0]; inv[1] = 1.f / lv[1];
            inv[2] = 1.f / lv[2]; inv[3] = 1.f / lv[3];
#pragma unroll
            for (int ct = 0; ct < 4; ++ct) {
                int col = 64 * w + 16 * ct + lm;
#pragma unroll
                for (int r = 0; r < 4; ++r) {
                    int n = n0 + rt * 16 + 4 * g + r;
                    size_t idx = ((size_t)(b * NN) + n) * CC + col;
                    out[idx] = x[idx] + gam * acc[rt][ct][r] * inv[r];
                }
            }
        }
    } else {
        bf16* pa = pacc + ((size_t)(bq * KS + ks)) * (64 * 256);
#pragma unroll
        for (int rt = 0; rt < 4; ++rt) {
#pragma unroll
            for (int ct = 0; ct < 4; ++ct) {
                int col = 64 * w + 16 * ct + lm;
#pragma unroll
                for (int r = 0; r < 4; ++r) {
                    int rowin = rt * 16 + 4 * g + r;
                    pa[rowin * 256 + col] = (bf16)acc[rt][ct][r];
                }
            }
        }
        if (g == 0) {
            int rowin = 16 * w + lm;
            size_t mo = ((size_t)(bq * KS + ks) * 64 + rowin) * 2;
            pml[mo + 0] = mrun;
            pml[mo + 1] = lrun;
        }
    }
}

// ---------------- combine: merge KS partials (bf16) + residual epilogue -----
__global__ __launch_bounds__(256) void combine_kernel(
    const bf16* __restrict__ pacc, const float* __restrict__ pml,
    const float* __restrict__ x, const float* __restrict__ gamma,
    float* __restrict__ out, int KS)
{
    int tid = threadIdx.x;
    int row = blockIdx.x * 4 + (tid >> 6);   // global row in [0, B*N)
    int lane = tid & 63;
    int bq = row >> 6;
    int r64 = row & 63;

    float m[4], l[4];
    float M = -3e38f;
    for (int ks = 0; ks < KS; ++ks) {
        size_t mo = ((size_t)(bq * KS + ks) * 64 + r64) * 2;
        m[ks] = pml[mo + 0];
        l[ks] = pml[mo + 1];
        M = fmaxf(M, m[ks]);
    }
    float L = 0.f;
    float wgt[4];
    for (int ks = 0; ks < KS; ++ks) {
        wgt[ks] = __expf(m[ks] - M);
        L += wgt[ks] * l[ks];
    }
    float s = gamma[0] / L;

    f32x4 a = {0.f, 0.f, 0.f, 0.f};
    for (int ks = 0; ks < KS; ++ks) {
        const bf16* pa = pacc + ((size_t)(bq * KS + ks) * 64 + r64) * 256;
        bf16x4 v = *(const bf16x4*)(pa + lane * 4);
        a[0] += wgt[ks] * (float)v[0]; a[1] += wgt[ks] * (float)v[1];
        a[2] += wgt[ks] * (float)v[2]; a[3] += wgt[ks] * (float)v[3];
    }
    const f32x4* xv = (const f32x4*)(x + (size_t)row * 256);
    f32x4 xi = xv[lane];
    f32x4 o;
    o[0] = xi[0] + s * a[0]; o[1] = xi[1] + s * a[1];
    o[2] = xi[2] + s * a[2]; o[3] = xi[3] + s * a[3];
    ((f32x4*)(out + (size_t)row * 256))[lane] = o;
}

extern "C" void kernel_launch(void* const* d_in, const int* in_sizes, int n_in,
                              void* d_out, int out_size, void* d_ws, size_t ws_size,
                              hipStream_t stream)
{
    const float* x     = (const float*)d_in[0];
    const float* Wq    = (const float*)d_in[1];
    const float* Wk    = (const float*)d_in[2];
    const float* Wv    = (const float*)d_in[3];
    const float* gamma = (const float*)d_in[4];
    float* out = (float*)d_out;

    char* ws = (char*)d_ws;
    bf16* WT = (bf16*)(ws);                  //   163,840 B
    bf16* qb = (bf16*)(ws + 163840);         // 1,048,576 B
    bf16* kb = (bf16*)(ws + 1212416);        // 1,048,576 B
    bf16* vt = (bf16*)(ws + 2260992);        // 8,388,608 B  (end 10,649,600)

    const size_t base = 10649600;
    // per-ks partials: acc = 256*64*256*2 B (bf16), ml = 256*64*2*4 B
    size_t need3 = base + (size_t)3 * (8388608 + 131072);
    int KS = (ws_size >= need3) ? 3 : 1;

    bf16*  pacc = (bf16*)(ws + base);
    float* pml  = (float*)(ws + base + (size_t)KS * 8388608);

    hipLaunchKernelGGL(prepw_kernel, dim3(320), dim3(256), 0, stream,
                       Wq, Wk, Wv, WT);
    hipLaunchKernelGGL(proj_kernel, dim3(512), dim3(256), 0, stream,
                       x, WT, qb, kb, vt);
    hipLaunchKernelGGL(attn_kernel, dim3(256 * KS), dim3(256), 0, stream,
                       qb, kb, vt, x, gamma, pacc, pml, out, KS);
    if (KS > 1) {
        hipLaunchKernelGGL(combine_kernel, dim3(BB * NN / 4), dim3(256), 0, stream,
                           pacc, pml, x, gamma, out, KS);
    }
}

// Round 6
// 91.860 us; speedup vs baseline: 1.2662x; 1.2662x over previous
//
#include <hip/hip_runtime.h>
#include <stdint.h>

#define BB 4
#define NN 4096
#define CC 256
#define DD 32

typedef __bf16 bf16;
typedef bf16 bf16x4 __attribute__((ext_vector_type(4)));
typedef bf16 bf16x8 __attribute__((ext_vector_type(8)));
typedef float f32x4 __attribute__((ext_vector_type(4)));
typedef unsigned int u32x4 __attribute__((ext_vector_type(4)));

// ---------------- prepw: build WT[320][256] = [Wq|Wk|Wv]^T (bf16) -----------
__global__ void prepw_kernel(const float* __restrict__ Wq,
                             const float* __restrict__ Wk,
                             const float* __restrict__ Wv,
                             bf16* __restrict__ WT)
{
    int i = blockIdx.x * 256 + threadIdx.x;
    if (i < 320 * 256) {
        int d = i >> 8, c = i & 255;
        float val;
        if (d < DD)          val = Wq[c * DD + d];
        else if (d < 2 * DD) val = Wk[c * DD + (d - DD)];
        else                 val = Wv[c * CC + (d - 2 * DD)];
        WT[i] = (bf16)val;
    }
}

// ---------------- proj: [q|k|v] = x @ [Wq|Wk|Wv], f32 x read + in-reg cast --
__global__ __launch_bounds__(256) void proj_kernel(
    const float* __restrict__ x, const bf16* __restrict__ WT,
    bf16* __restrict__ qb, bf16* __restrict__ kb, bf16* __restrict__ vt)
{
    int b = blockIdx.x >> 7, nt = blockIdx.x & 127;   // 128 tiles of 32 rows
    int n0 = nt << 5;
    int tid = threadIdx.x;
    int w = tid >> 6, lane = tid & 63;
    int lm = lane & 15, g = lane >> 4;
    int rw = w >> 1;    // row half
    int ch = w & 1;     // ct half

    f32x4 acc[10];
    f32x4 zero4 = {0.f, 0.f, 0.f, 0.f};
#pragma unroll
    for (int i = 0; i < 10; ++i) acc[i] = zero4;

    const float* xrow = x + ((size_t)(b * NN) + n0 + rw * 16 + lm) * CC;
    for (int kc = 0; kc < 8; ++kc) {
        f32x4 a0 = *(const f32x4*)(xrow + kc * 32 + g * 8);
        f32x4 a1 = *(const f32x4*)(xrow + kc * 32 + g * 8 + 4);
        bf16x8 a;
        a[0] = (bf16)a0[0]; a[1] = (bf16)a0[1]; a[2] = (bf16)a0[2]; a[3] = (bf16)a0[3];
        a[4] = (bf16)a1[0]; a[5] = (bf16)a1[1]; a[6] = (bf16)a1[2]; a[7] = (bf16)a1[3];
#pragma unroll
        for (int ct = 0; ct < 10; ++ct) {
            int ctg = ch * 10 + ct;
            bf16x8 wv = *(const bf16x8*)(WT + (ctg * 16 + lm) * 256 + kc * 32 + g * 8);
            acc[ct] = __builtin_amdgcn_mfma_f32_16x16x32_bf16(a, wv, acc[ct], 0, 0, 0);
        }
    }

#pragma unroll
    for (int ct = 0; ct < 10; ++ct) {
        int ctg = ch * 10 + ct;
        int col = ctg * 16 + lm;
        if (ctg < 4) {
#pragma unroll
            for (int r = 0; r < 4; ++r) {
                int n = n0 + rw * 16 + g * 4 + r;
                bf16 hv = (bf16)acc[ct][r];
                if (ctg < 2) qb[((size_t)(b * NN) + n) * DD + col] = hv;
                else         kb[((size_t)(b * NN) + n) * DD + (col - DD)] = hv;
            }
        } else {
            int c = col - 64;
            int tile = nt >> 1;
            int nbase = ((nt & 1) * 32 + rw * 16 + g * 4) ^ ((c & 7) << 3);
            bf16x4 pk;
            pk[0] = (bf16)acc[ct][0]; pk[1] = (bf16)acc[ct][1];
            pk[2] = (bf16)acc[ct][2]; pk[3] = (bf16)acc[ct][3];
            size_t off = (((size_t)(b * 64 + tile)) * 256 + c) * 64 + nbase;
            *(bf16x4*)(vt + off) = pk;
        }
    }
}

// ============ attn v6: pipelined — QK(t)+PV(t-1) burst, softmax overlaps ====
// Block: 64 q-rows x key-slice, 4 waves. Wave w: QK^T (swapped mfma(K,Q)) for
// q-rows 16w..16w+15; lane holds S[qrow=lm][key=16t+4g+r]. PV channel-split
// (wave w -> chans 64w..64w+63, V quarter in regs, double-buffered). P/alpha
// via parity-alternating LDS. PV lags QK by one tile: iteration t issues
// QK(t)+PV(t-1) as one MFMA burst, then softmax(t) on VALU overlaps the MFMA
// drain. One raw s_barrier/iter (no vmcnt drain; prefetches stay in flight).

#define LOADK(KT_, KF) { \
    const bf16* kbase_ = kb + ((size_t)(b * NN) + (size_t)(KT_) * 64) * DD + g * 8; \
    KF[0] = *(const bf16x8*)(kbase_ + (lm +  0) * DD); \
    KF[1] = *(const bf16x8*)(kbase_ + (lm + 16) * DD); \
    KF[2] = *(const bf16x8*)(kbase_ + (lm + 32) * DD); \
    KF[3] = *(const bf16x8*)(kbase_ + (lm + 48) * DD); }

#define LOADV(KT_, VB) { \
    const bf16* vtile_ = vt + ((size_t)(b * 64 + (KT_))) * 16384; \
    _Pragma("unroll") \
    for (int ct_ = 0; ct_ < 4; ++ct_) { \
        int c_ = 64 * w + 16 * ct_ + lm; \
        const bf16* vrow_ = vtile_ + c_ * 64; \
        int vsw_ = (c_ & 7) << 3; \
        VB[ct_][0] = *(const bf16x8*)(vrow_ + ((8 * g) ^ vsw_)); \
        VB[ct_][1] = *(const bf16x8*)(vrow_ + ((32 + 8 * g) ^ vsw_)); \
    } }

// PV for tile whose P/alpha live in LDS parity PRV_, V fragments in VB.
#define PVBLOCK(PRV_, VB) { \
    const float* alph_p = (const float*)(lds + 16384 + (PRV_) * 512); \
    const uint32_t* flg_p = (const uint32_t*)(lds + 16384 + (PRV_) * 512 + 256); \
    const unsigned char* Pp_ = lds + (PRV_) * 8192; \
    u32x4 fl_ = *(const u32x4*)flg_p; \
    if ((fl_[0] & fl_[1] & fl_[2] & fl_[3]) == 0u) { \
        _Pragma("unroll") for (int rt_ = 0; rt_ < 4; ++rt_) { \
            f32x4 a_ = *(const f32x4*)(alph_p + rt_ * 16 + 4 * g); \
            _Pragma("unroll") for (int ct_ = 0; ct_ < 4; ++ct_) { \
                acc[rt_][ct_][0] *= a_[0]; acc[rt_][ct_][1] *= a_[1]; \
                acc[rt_][ct_][2] *= a_[2]; acc[rt_][ct_][3] *= a_[3]; \
            } \
        } \
    } \
    int psw_ = (lm & 7) << 4; \
    _Pragma("unroll") for (int rt_ = 0; rt_ < 4; ++rt_) { \
        const unsigned char* pr_ = Pp_ + (rt_ * 16 + lm) * 128; \
        bf16x8 pa0_ = *(const bf16x8*)(pr_ + (( 0 + 16 * g) ^ psw_)); \
        bf16x8 pa1_ = *(const bf16x8*)(pr_ + ((64 + 16 * g) ^ psw_)); \
        _Pragma("unroll") for (int ct_ = 0; ct_ < 4; ++ct_) { \
            acc[rt_][ct_] = __builtin_amdgcn_mfma_f32_16x16x32_bf16(pa0_, VB[ct_][0], acc[rt_][ct_], 0, 0, 0); \
            acc[rt_][ct_] = __builtin_amdgcn_mfma_f32_16x16x32_bf16(pa1_, VB[ct_][1], acc[rt_][ct_], 0, 0, 0); \
        } \
    } \
}

// One pipeline stage. KF holds K(T_); KFN gets K(T_+1); VBP holds V(T_-1)
// (consumed by PV, then refilled with V(T_+1)). vb[T_&1] holds V(T_) untouched.
#define STEP(T_, KF, KFN, VBP, DOPV) { \
    const int cur_ = (T_) & 1; \
    __builtin_amdgcn_s_setprio(1); \
    f32x4 sv0 = __builtin_amdgcn_mfma_f32_16x16x32_bf16(KF[0], qf, zero4, 0, 0, 0); \
    f32x4 sv1 = __builtin_amdgcn_mfma_f32_16x16x32_bf16(KF[1], qf, zero4, 0, 0, 0); \
    f32x4 sv2 = __builtin_amdgcn_mfma_f32_16x16x32_bf16(KF[2], qf, zero4, 0, 0, 0); \
    f32x4 sv3 = __builtin_amdgcn_mfma_f32_16x16x32_bf16(KF[3], qf, zero4, 0, 0, 0); \
    int ktn_ = ((T_) + 1 < kt1) ? ((T_) + 1) : (kt1 - 1); \
    LOADK(ktn_, KFN); \
    if (DOPV) { PVBLOCK(cur_ ^ 1, VBP); } \
    __builtin_amdgcn_s_setprio(0); \
    LOADV(ktn_, VBP); \
    float mx_ = fmaxf(fmaxf(fmaxf(sv0[0], sv0[1]), fmaxf(sv0[2], sv0[3])), \
                      fmaxf(fmaxf(sv1[0], sv1[1]), fmaxf(sv1[2], sv1[3]))); \
    mx_ = fmaxf(mx_, fmaxf(fmaxf(sv2[0], sv2[1]), fmaxf(sv2[2], sv2[3]))); \
    mx_ = fmaxf(mx_, fmaxf(fmaxf(sv3[0], sv3[1]), fmaxf(sv3[2], sv3[3]))); \
    mx_ = fmaxf(mx_, __shfl_xor(mx_, 16)); \
    mx_ = fmaxf(mx_, __shfl_xor(mx_, 32)); \
    float alpha_; \
    int wave_ok_ = __all(mx_ <= mrun + 8.0f); \
    if (!wave_ok_) { float mn_ = fmaxf(mrun, mx_); alpha_ = __expf(mrun - mn_); mrun = mn_; } \
    else alpha_ = 1.0f; \
    float ssum_; \
    { \
        _Pragma("unroll") for (int j_ = 0; j_ < 4; ++j_) sv0[j_] = __expf(sv0[j_] - mrun); \
        _Pragma("unroll") for (int j_ = 0; j_ < 4; ++j_) sv1[j_] = __expf(sv1[j_] - mrun); \
        _Pragma("unroll") for (int j_ = 0; j_ < 4; ++j_) sv2[j_] = __expf(sv2[j_] - mrun); \
        _Pragma("unroll") for (int j_ = 0; j_ < 4; ++j_) sv3[j_] = __expf(sv3[j_] - mrun); \
        f32x4 t_ = (sv0 + sv1) + (sv2 + sv3); \
        ssum_ = (t_[0] + t_[1]) + (t_[2] + t_[3]); \
        ssum_ += __shfl_xor(ssum_, 16); \
        ssum_ += __shfl_xor(ssum_, 32); \
    } \
    lrun = lrun * alpha_ + ssum_; \
    unsigned char* Pb_ = lds + cur_ * 8192; \
    { \
        int rb_ = (16 * w + lm) * 128; \
        int sw_ = (lm & 7) << 4; \
        bf16x4 pk_; \
        pk_[0] = (bf16)sv0[0]; pk_[1] = (bf16)sv0[1]; pk_[2] = (bf16)sv0[2]; pk_[3] = (bf16)sv0[3]; \
        *(bf16x4*)(Pb_ + rb_ + (( 0 + 8 * g) ^ sw_)) = pk_; \
        pk_[0] = (bf16)sv1[0]; pk_[1] = (bf16)sv1[1]; pk_[2] = (bf16)sv1[2]; pk_[3] = (bf16)sv1[3]; \
        *(bf16x4*)(Pb_ + rb_ + ((32 + 8 * g) ^ sw_)) = pk_; \
        pk_[0] = (bf16)sv2[0]; pk_[1] = (bf16)sv2[1]; pk_[2] = (bf16)sv2[2]; pk_[3] = (bf16)sv2[3]; \
        *(bf16x4*)(Pb_ + rb_ + ((64 + 8 * g) ^ sw_)) = pk_; \
        pk_[0] = (bf16)sv3[0]; pk_[1] = (bf16)sv3[1]; pk_[2] = (bf16)sv3[2]; pk_[3] = (bf16)sv3[3]; \
        *(bf16x4*)(Pb_ + rb_ + ((96 + 8 * g) ^ sw_)) = pk_; \
    } \
    float* alph_ = (float*)(lds + 16384 + cur_ * 512); \
    uint32_t* flg_ = (uint32_t*)(lds + 16384 + cur_ * 512 + 256); \
    if (g == 0) alph_[16 * w + lm] = alpha_; \
    if (lane == 0) flg_[w] = (uint32_t)wave_ok_; \
    asm volatile("s_waitcnt lgkmcnt(0)" ::: "memory"); \
    __builtin_amdgcn_s_barrier(); \
    asm volatile("" ::: "memory"); \
}

__global__ __launch_bounds__(256, 2) void attn_kernel(
    const bf16* __restrict__ qb, const bf16* __restrict__ kb,
    const bf16* __restrict__ vt, const float* __restrict__ x,
    const float* __restrict__ gamma, bf16* __restrict__ pacc,
    float* __restrict__ pml, float* __restrict__ out, int KS)
{
    // 2 x 8KB P buffers + 2 x 512B meta (alphas f32[64] @+0, flags u32[4] @+256)
    __shared__ __align__(16) unsigned char lds[17408];
    int bid = blockIdx.x;
    int b, qt, ks;
    if (KS == 2) {
        // XCD-aware decode: batch b -> XCDs {2b,2b+1} so vt/kb stay L2-resident
        int xcd = bid & 7, slot = bid >> 3;      // 512 blocks: slot in [0,64)
        b = xcd >> 1;
        int idx = (xcd & 1) * 64 + slot;         // [0,128) within batch
        qt = idx >> 1; ks = idx & 1;
    } else {
        ks = bid % KS; int t = bid / KS; b = t >> 6; qt = t & 63;
    }
    int bq = b * 64 + qt;
    int n0 = qt << 6;
    int tid = threadIdx.x;
    int w = tid >> 6, lane = tid & 63;
    int lm = lane & 15, g = lane >> 4;

    // Q fragment (MFMA B-operand: col=qrow=lm, k=8g..8g+7)
    bf16x8 qf = *(const bf16x8*)(qb + ((size_t)(b * NN) + n0 + w * 16 + lm) * DD + g * 8);

    f32x4 acc[4][4]; // [row-tile][chan-tile], rows rt*16+4g+r, chans 64w+16ct+lm
    f32x4 zero4 = {0.f, 0.f, 0.f, 0.f};
#pragma unroll
    for (int i = 0; i < 4; ++i)
#pragma unroll
        for (int j = 0; j < 4; ++j) acc[i][j] = zero4;
    float mrun = -1e30f, lrun = 0.f;

    int KT = 64 / KS;
    int kt0 = ks * KT;          // even
    int kt1 = kt0 + KT;         // KT even

    bf16x8 kfA[4], kfB[4];
    bf16x8 vbA[4][2], vbB[4][2];
    LOADK(kt0, kfA);
    LOADV(kt0, vbA);

    // first stage: QK(kt0), loads K/V(kt0+1), no PV; P(kt0) -> parity 0
    STEP(kt0, kfA, kfB, vbB, 0);

    int kt = kt0 + 1;
    while (kt + 2 <= kt1) {
        STEP(kt,     kfB, kfA, vbA, 1);   // odd t: PV(t-1) parity0, V(t-1)=vbA
        STEP(kt + 1, kfA, kfB, vbB, 1);   // even t: PV(t-1) parity1, V(t-1)=vbB
        kt += 2;
    }
    if (kt < kt1) {                       // kt = kt1-1 (odd)
        STEP(kt, kfB, kfA, vbA, 1);
    }
    // trailing PV for last tile: P parity (kt1-1)&1 = 1, V in vbB
    PVBLOCK(1, vbB);

    if (KS == 1) {
        __syncthreads();
        float* lsh = (float*)(lds + 16384);
        if (g == 0) lsh[16 * w + lm] = lrun;
        __syncthreads();
        float gam = gamma[0];
#pragma unroll
        for (int rt = 0; rt < 4; ++rt) {
            f32x4 lv = *(const f32x4*)(lsh + rt * 16 + 4 * g);
            f32x4 inv;
            inv[0] = 1.f / lv[0]; inv[1] = 1.f / lv[1];
            inv[2] = 1.f / lv[2]; inv[3] = 1.f / lv[3];
#pragma unroll
            for (int ct = 0; ct < 4; ++ct) {
                int col = 64 * w + 16 * ct + lm;
#pragma unroll
                for (int r = 0; r < 4; ++r) {
                    int n = n0 + rt * 16 + 4 * g + r;
                    size_t idx = ((size_t)(b * NN) + n) * CC + col;
                    out[idx] = x[idx] + gam * acc[rt][ct][r] * inv[r];
                }
            }
        }
    } else {
        bf16* pa = pacc + ((size_t)(bq * KS + ks)) * (64 * 256);
#pragma unroll
        for (int rt = 0; rt < 4; ++rt) {
#pragma unroll
            for (int ct = 0; ct < 4; ++ct) {
                int col = 64 * w + 16 * ct + lm;
#pragma unroll
                for (int r = 0; r < 4; ++r) {
                    int rowin = rt * 16 + 4 * g + r;
                    pa[rowin * 256 + col] = (bf16)acc[rt][ct][r];
                }
            }
        }
        if (g == 0) {
            int rowin = 16 * w + lm;
            size_t mo = ((size_t)(bq * KS + ks) * 64 + rowin) * 2;
            pml[mo + 0] = mrun;
            pml[mo + 1] = lrun;
        }
    }
}

// ---------------- combine: merge KS partials (bf16) + residual epilogue -----
__global__ __launch_bounds__(256) void combine_kernel(
    const bf16* __restrict__ pacc, const float* __restrict__ pml,
    const float* __restrict__ x, const float* __restrict__ gamma,
    float* __restrict__ out, int KS)
{
    int tid = threadIdx.x;
    int row = blockIdx.x * 4 + (tid >> 6);   // global row in [0, B*N)
    int lane = tid & 63;
    int bq = row >> 6;
    int r64 = row & 63;

    float m[4], l[4];
    float M = -3e38f;
    for (int ks = 0; ks < KS; ++ks) {
        size_t mo = ((size_t)(bq * KS + ks) * 64 + r64) * 2;
        m[ks] = pml[mo + 0];
        l[ks] = pml[mo + 1];
        M = fmaxf(M, m[ks]);
    }
    float L = 0.f;
    float wgt[4];
    for (int ks = 0; ks < KS; ++ks) {
        wgt[ks] = __expf(m[ks] - M);
        L += wgt[ks] * l[ks];
    }
    float s = gamma[0] / L;

    f32x4 a = {0.f, 0.f, 0.f, 0.f};
    for (int ks = 0; ks < KS; ++ks) {
        const bf16* pa = pacc + ((size_t)(bq * KS + ks) * 64 + r64) * 256;
        bf16x4 v = *(const bf16x4*)(pa + lane * 4);
        a[0] += wgt[ks] * (float)v[0]; a[1] += wgt[ks] * (float)v[1];
        a[2] += wgt[ks] * (float)v[2]; a[3] += wgt[ks] * (float)v[3];
    }
    const f32x4* xv = (const f32x4*)(x + (size_t)row * 256);
    f32x4 xi = xv[lane];
    f32x4 o;
    o[0] = xi[0] + s * a[0]; o[1] = xi[1] + s * a[1];
    o[2] = xi[2] + s * a[2]; o[3] = xi[3] + s * a[3];
    ((f32x4*)(out + (size_t)row * 256))[lane] = o;
}

extern "C" void kernel_launch(void* const* d_in, const int* in_sizes, int n_in,
                              void* d_out, int out_size, void* d_ws, size_t ws_size,
                              hipStream_t stream)
{
    const float* x     = (const float*)d_in[0];
    const float* Wq    = (const float*)d_in[1];
    const float* Wk    = (const float*)d_in[2];
    const float* Wv    = (const float*)d_in[3];
    const float* gamma = (const float*)d_in[4];
    float* out = (float*)d_out;

    char* ws = (char*)d_ws;
    bf16* WT = (bf16*)(ws);                  //   163,840 B
    bf16* qb = (bf16*)(ws + 163840);         // 1,048,576 B
    bf16* kb = (bf16*)(ws + 1212416);        // 1,048,576 B
    bf16* vt = (bf16*)(ws + 2260992);        // 8,388,608 B  (end 10,649,600)

    const size_t base = 10649600;
    // per-ks partials: acc = 256*64*256*2 B (bf16), ml = 256*64*2*4 B
    size_t need2 = base + (size_t)2 * (8388608 + 131072);
    int KS = (ws_size >= need2) ? 2 : 1;

    bf16*  pacc = (bf16*)(ws + base);
    float* pml  = (float*)(ws + base + (size_t)KS * 8388608);

    hipLaunchKernelGGL(prepw_kernel, dim3(320), dim3(256), 0, stream,
                       Wq, Wk, Wv, WT);
    hipLaunchKernelGGL(proj_kernel, dim3(512), dim3(256), 0, stream,
                       x, WT, qb, kb, vt);
    hipLaunchKernelGGL(attn_kernel, dim3(256 * KS), dim3(256), 0, stream,
                       qb, kb, vt, x, gamma, pacc, pml, out, KS);
    if (KS > 1) {
        hipLaunchKernelGGL(combine_kernel, dim3(BB * NN / 4), dim3(256), 0, stream,
                           pacc, pml, x, gamma, out, KS);
    }
}